// Round 8
// baseline (190.681 us; speedup 1.0000x reference)
//
#include <hip/hip_runtime.h>
#include <stdint.h>

#define DI static __device__ __forceinline__

typedef __attribute__((ext_vector_type(8))) short bh8;   // 8 x bf16 (4 VGPRs)
typedef __attribute__((ext_vector_type(4))) float f4;    // MFMA accumulator

DI short f2bf(float f) {             // fp32 -> bf16 (RNE)
  unsigned u = __float_as_uint(f);
  u += 0x7fffu + ((u >> 16) & 1u);
  return (short)(u >> 16);
}

DI unsigned pkbf(float a, float b) { // [bf16(a) | bf16(b)<<16], round-half-up
  unsigned ua = __float_as_uint(a) + 0x8000u;
  unsigned ub = __float_as_uint(b) + 0x8000u;
  return __builtin_amdgcn_perm(ub, ua, 0x07060302u);
}

DI unsigned char f2fp8(float f) {    // fp32 -> fp8 e4m3 (1 byte)
  return (unsigned char)(__builtin_amdgcn_cvt_pk_fp8_f32(f, f, 0, false) & 0xff);
}

DI void gll16(const void* g, void* l) {  // 16B global -> LDS async
  __builtin_amdgcn_global_load_lds(
      (const __attribute__((address_space(1))) unsigned int*)g,
      (__attribute__((address_space(3))) unsigned int*)l, 16, 0, 0);
}

DI f4 mfma16(bh8 a, bh8 b, f4 c) {
  return __builtin_amdgcn_mfma_f32_16x16x32_bf16(a, b, c, 0, 0, 0);
}

DI f4 mfma8(long a, long b, f4 c) {  // fp8 e4m3 x e4m3, K=32
  return __builtin_amdgcn_mfma_f32_16x16x32_fp8_fp8(a, b, c, 0, 0, 0);
}

DI bh8 ld8(const short* p) { return *(const bh8*)p; }

// ---------------------------------------------------------------------------
// prep_k: fused weight-transpose (roles 0..3) + LayerNorm (roles 4..5).
// ---------------------------------------------------------------------------
__global__ __launch_bounds__(256) void prep_k(
    const float* __restrict__ kv, const float* __restrict__ qi,
    const float* __restrict__ kw, const float* __restrict__ kbv,
    const float* __restrict__ qw, const float* __restrict__ qbv,
    const float* __restrict__ Wk, const float* __restrict__ Wq,
    const float* __restrict__ Wv, const float* __restrict__ Wp,
    short* __restrict__ kvn, short* __restrict__ qn,
    short* __restrict__ Wt)
{
  __shared__ char sm[16 * 516 * 4 + 128];
  int role = blockIdx.y;
  int bx = blockIdx.x;
  int tid = threadIdx.x;

  if (role < 4) {                       // ---- weight transpose + cvt ----
    if (bx >= 256) return;
    float (*ts)[33] = (float(*)[33])sm;
    const float* w = (role == 0) ? Wk : (role == 1) ? Wq : (role == 2) ? Wv : Wp;
    short* o = Wt + ((size_t)role << 18);
    int c0 = (bx & 15) << 5, r0 = (bx >> 4) << 5;
    int tx = tid & 31, ty = tid >> 5;   // 32 x 8
#pragma unroll
    for (int k = 0; k < 32; k += 8)
      ts[ty + k][tx] = w[((size_t)(r0 + ty + k) << 9) + c0 + tx];
    __syncthreads();
#pragma unroll
    for (int k = 0; k < 32; k += 8)
      o[((size_t)(c0 + ty + k) << 9) + r0 + tx] = f2bf(ts[tx][ty + k]);
    return;
  }

  // ---- LayerNorm over C=512, fused [B,C,T] -> [token,C] transpose ----
  float (*xs)[516] = (float(*)[516])sm;
  float* smean = (float*)(sm + 16 * 516 * 4);
  float* srstd = smean + 16;
  int which = role - 4;
  const float* x = which ? qi : kv;
  const float* w = which ? qw : kw;
  const float* bb = which ? qbv : kbv;
  short* o = which ? qn : kvn;
  int b = bx >> 6;
  int t0 = (bx & 63) << 4;
  const float* xb = x + ((size_t)b << 19) + (size_t)t0;
#pragma unroll
  for (int k = 0; k < 8; k++) {
    int idx = (k << 8) + tid;            // 0..2047
    int c = idx >> 2, tt = (idx & 3) << 2;
    float4 v = *(const float4*)(xb + ((size_t)c << 10) + tt);
    xs[tt + 0][c] = v.x; xs[tt + 1][c] = v.y;
    xs[tt + 2][c] = v.z; xs[tt + 3][c] = v.w;
  }
  __syncthreads();
  {
    int t = tid >> 4, cp = tid & 15;
    float s = 0.f, s2 = 0.f;
#pragma unroll
    for (int k = 0; k < 8; k++) {
      float4 v = *(const float4*)&xs[t][(cp << 2) + (k << 6)];
      s  += v.x + v.y + v.z + v.w;
      s2 += v.x * v.x + v.y * v.y + v.z * v.z + v.w * v.w;
    }
#pragma unroll
    for (int m = 1; m < 16; m <<= 1) {
      s  += __shfl_xor(s,  m);
      s2 += __shfl_xor(s2, m);
    }
    if (cp == 0) {
      float mean = s * (1.f / 512.f);
      float var  = s2 * (1.f / 512.f) - mean * mean;
      smean[t] = mean;
      srstd[t] = rsqrtf(var + 1e-5f);
    }
  }
  __syncthreads();
#pragma unroll
  for (int k = 0; k < 8; k++) {
    int idx = (k << 8) + tid;
    int t = idx >> 7, c = (idx & 127) << 2;
    float4 v = *(const float4*)&xs[t][c];
    float4 wv = *(const float4*)(w + c);
    float4 bv4 = *(const float4*)(bb + c);
    float mu = smean[t], rs = srstd[t];
    float r0 = (v.x - mu) * rs * wv.x + bv4.x;
    float r1 = (v.y - mu) * rs * wv.y + bv4.y;
    float r2 = (v.z - mu) * rs * wv.z + bv4.z;
    float r3 = (v.w - mu) * rs * wv.w + bv4.w;
    uint2 pk; pk.x = pkbf(r0, r1); pk.y = pkbf(r2, r3);
    *(uint2*)(o + (((size_t)(b << 10) + t0 + t) << 9) + c) = pk;
  }
}

// ---------------------------------------------------------------------------
// Fused K/Q/V projection GEMM. 128x128 tile, BK=64, xor bank swizzle.
// fp8 outputs for attn's direct-global fragment loads:
// z=0 K: [bh][ck][p=pi(t&255)][d]   (pi = 16x16 key transpose, d plain)
// z=1 Q: [bh][t][d], pre-scaled by csc = log2(e)/8
// z=2 V: [bh][d][t]  (plain transposed)
// ---------------------------------------------------------------------------
__global__ __launch_bounds__(256, 3) void gemm_qkv_k(
    const short* __restrict__ kvn, const short* __restrict__ qn,
    const short* __restrict__ Wt,
    const float* __restrict__ bk, const float* __restrict__ bq,
    const float* __restrict__ bv,
    unsigned char* __restrict__ kb8, unsigned char* __restrict__ qb8,
    unsigned char* __restrict__ vb8)
{
  __shared__ short As[128 * 64];   // 16 KB
  __shared__ short Bs[128 * 64];   // 16 KB
  int z = blockIdx.z;
  const short* A; const short* Bt; const float* bias;
  int m0, n0;
  if (z == 0)      { A = kvn;            Bt = Wt;             bias = bk; }
  else if (z == 1) { A = qn;             Bt = Wt + (1 << 18); bias = bq; }
  else             { A = Wt + (2 << 18); Bt = kvn;            bias = bv; }
  if (z == 2) { m0 = blockIdx.y << 7; n0 = blockIdx.x << 7; }
  else        { m0 = blockIdx.x << 7; n0 = blockIdx.y << 7; }
  int tid = threadIdx.x;
  int lane = tid & 63, wid = tid >> 6;
  int r = lane & 15, g = lane >> 4;
  int wrow = (wid >> 1) << 6, wcol = (wid & 1) << 6;
  f4 acc[4][4];
#pragma unroll
  for (int i = 0; i < 4; i++)
#pragma unroll
    for (int j = 0; j < 4; j++) {
      acc[i][j][0] = 0.f; acc[i][j][1] = 0.f;
      acc[i][j][2] = 0.f; acc[i][j][3] = 0.f;
    }
  for (int k0 = 0; k0 < 512; k0 += 64) {
    __syncthreads();
#pragma unroll
    for (int it = 0; it < 4; it++) {
      int n = (it << 8) + tid;           // 16B-unit index, lane-contiguous
      int row = n >> 3;
      int c = (n & 7) ^ (row & 7);       // source chunk for swizzled slot
      gll16(A  + ((size_t)(m0 + row) << 9) + k0 + (c << 3), As + (n << 3));
      gll16(Bt + ((size_t)(n0 + row) << 9) + k0 + (c << 3), Bs + (n << 3));
    }
    __syncthreads();
    bh8 a[2][4], b[2][4];
#pragma unroll
    for (int ks = 0; ks < 2; ks++) {
#pragma unroll
      for (int i = 0; i < 4; i++) {
        int R = wrow + (i << 4) + r;
        a[ks][i] = ld8(As + (R << 6) + ((((ks << 2) + g) ^ (R & 7)) << 3));
      }
#pragma unroll
      for (int j = 0; j < 4; j++) {
        int R = wcol + (j << 4) + r;
        b[ks][j] = ld8(Bs + (R << 6) + ((((ks << 2) + g) ^ (R & 7)) << 3));
      }
    }
#pragma unroll
    for (int ks = 0; ks < 2; ks++)
#pragma unroll
      for (int i = 0; i < 4; i++)
#pragma unroll
        for (int j = 0; j < 4; j++)
          acc[i][j] = mfma16(a[ks][i], b[ks][j], acc[i][j]);
  }
  const float csc = 0.18033688011112042f;   // log2(e)/8
  // epilogue: C/D layout col = lane&15, row = (lane>>4)*4 + reg
#pragma unroll
  for (int i = 0; i < 4; i++) {
#pragma unroll
    for (int j = 0; j < 4; j++) {
      int mm = m0 + wrow + (i << 4) + (g << 2);
      int nn = n0 + wcol + (j << 4) + r;
      if (z == 0) {                      // K: pi-permuted rows, plain d
        float bvv = bias[nn];
        int h = nn >> 6, d = nn & 63;
#pragma unroll
        for (int q = 0; q < 4; q++) {
          int m = mm + q;
          int bb = m >> 10, t = m & 1023;
          int c = t & 255;
          int p = ((c & 15) << 4) | (c >> 4);
          size_t base = ((size_t)((bb * 8 + h) * 4 + (t >> 8)) << 14);
          kb8[base + (p << 6) + d] = f2fp8(acc[i][j][q] + bvv);
        }
      } else if (z == 1) {               // Q: plain fp8 [bh][t][d], x csc
        float bvv = bias[nn];
        int h = nn >> 6, d = nn & 63;
#pragma unroll
        for (int q = 0; q < 4; q++) {
          int m = mm + q;
          int bb = m >> 10, t = m & 1023;
          qb8[((((size_t)(bb * 8 + h)) << 10) + t) * 64 + d] =
              f2fp8((acc[i][j][q] + bvv) * csc);
        }
      } else {                           // V: plain fp8 [bh][d][t]
        int bb = nn >> 10, t = nn & 1023;
#pragma unroll
        for (int q = 0; q < 4; q++) {
          int m = mm + q;
          int h = m >> 6, d = m & 63;
          vb8[((size_t)(bb * 8 + h) << 16) + (d << 10) + t] =
              f2fp8(acc[i][j][q] + bias[m]);
        }
      }
    }
  }
}

// ---------------------------------------------------------------------------
// Output projection: C[c,token] = Wp^T @ y^T, 64x128 tile, BK=64.
// ---------------------------------------------------------------------------
__global__ __launch_bounds__(256, 2) void gemm_proj_k(
    const short* __restrict__ A, const short* __restrict__ Bt,
    const float* __restrict__ bias, float* __restrict__ outp,
    const float* __restrict__ resid)
{
  __shared__ short As[64 * 64];    // 8 KB
  __shared__ short Bs[128 * 64];   // 16 KB
  int m0 = blockIdx.y << 6, n0 = blockIdx.x << 7;
  int tid = threadIdx.x;
  int lane = tid & 63, wid = tid >> 6;
  int r = lane & 15, g = lane >> 4;
  int wrow = (wid >> 1) << 5, wcol = (wid & 1) << 6;   // wave: 32 x 64
  f4 acc[2][4];
#pragma unroll
  for (int i = 0; i < 2; i++)
#pragma unroll
    for (int j = 0; j < 4; j++) {
      acc[i][j][0] = 0.f; acc[i][j][1] = 0.f;
      acc[i][j][2] = 0.f; acc[i][j][3] = 0.f;
    }
  for (int k0 = 0; k0 < 512; k0 += 64) {
    __syncthreads();
#pragma unroll
    for (int it = 0; it < 2; it++) {     // As: 512 units
      int n = (it << 8) + tid;
      int row = n >> 3;
      int c = (n & 7) ^ (row & 7);
      gll16(A + ((size_t)(m0 + row) << 9) + k0 + (c << 3), As + (n << 3));
    }
#pragma unroll
    for (int it = 0; it < 4; it++) {     // Bs: 1024 units
      int n = (it << 8) + tid;
      int row = n >> 3;
      int c = (n & 7) ^ (row & 7);
      gll16(Bt + ((size_t)(n0 + row) << 9) + k0 + (c << 3), Bs + (n << 3));
    }
    __syncthreads();
    bh8 a[2][2], b[2][4];
#pragma unroll
    for (int ks = 0; ks < 2; ks++) {
#pragma unroll
      for (int i = 0; i < 2; i++) {
        int R = wrow + (i << 4) + r;
        a[ks][i] = ld8(As + (R << 6) + ((((ks << 2) + g) ^ (R & 7)) << 3));
      }
#pragma unroll
      for (int j = 0; j < 4; j++) {
        int R = wcol + (j << 4) + r;
        b[ks][j] = ld8(Bs + (R << 6) + ((((ks << 2) + g) ^ (R & 7)) << 3));
      }
    }
#pragma unroll
    for (int ks = 0; ks < 2; ks++)
#pragma unroll
      for (int i = 0; i < 2; i++)
#pragma unroll
        for (int j = 0; j < 4; j++)
          acc[i][j] = mfma16(a[ks][i], b[ks][j], acc[i][j]);
  }
#pragma unroll
  for (int i = 0; i < 2; i++) {
#pragma unroll
    for (int j = 0; j < 4; j++) {
      int mm = m0 + wrow + (i << 4) + (g << 2);
      int nn = n0 + wcol + (j << 4) + r;
      int bb = nn >> 10, t = nn & 1023;
#pragma unroll
      for (int q = 0; q < 4; q++) {
        int m = mm + q;
        size_t ad = ((((size_t)bb << 9) + m) << 10) + t;
        outp[ad] = acc[i][j][q] + bias[m] + resid[ad];
      }
    }
  }
}

// ---------------------------------------------------------------------------
// Flash attention v2: BARRIER-FREE, zero K/V LDS. fp8 K/V fragments are read
// directly from global (B-frag = 8 contiguous bytes; 100% sector efficiency):
//   K image [bh][ck][p=pi(key)][d], V image [bh][d][t], Q [bh][t][d] x csc.
// Only P round-trips through LDS (rows are wave-private -> no syncthreads).
// Softmax: P = exp2(min(S, 8.5)) (csc folded into Q; shift dropped - cancels
// in normalization; clamp keeps P <= 362 < 448 e4m3 max, NaN-safe).
// block = 256 (4 waves), wave owns 32 q-rows; 4 chunks x 256 keys.
// ---------------------------------------------------------------------------
__global__ __launch_bounds__(256, 2) void attn_k(
    const unsigned char* __restrict__ qb8, const unsigned char* __restrict__ kb8,
    const unsigned char* __restrict__ vb8, short* __restrict__ yo)
{
  __shared__ char Ps[32768];       // [row][256 key fp8], 16B-chunk xor (row&15)
  int h = blockIdx.x, b = blockIdx.z;
  int qt0 = blockIdx.y << 7;
  int tid = threadIdx.x, lane = tid & 63, wid = tid >> 6;
  int r = lane & 15, g = lane >> 4;
  int wbase = wid << 5;
  size_t bh = (size_t)(b * 8 + h);
  const unsigned char* Qg = qb8 + ((bh << 10) + qt0) * 64;
  const unsigned char* Kg = kb8 + (bh << 16);     // 4 chunks x 16 KB
  const unsigned char* Vg = vb8 + (bh << 16);     // [d][1024 t]

  // Q A-fragments: direct fp8 b64 loads (csc pre-folded by producer)
  long qf8[2][2];
#pragma unroll
  for (int i = 0; i < 2; i++)
#pragma unroll
    for (int ksd = 0; ksd < 2; ksd++)
      qf8[i][ksd] = *(const long*)(Qg +
          ((size_t)(wbase + (i << 4) + r) << 6) + (((ksd << 2) + g) << 3));

  const long ONES = 0x3838383838383838L;   // fp8 e4m3 1.0 x8

  f4 oac[2][4], sacc[2];
#pragma unroll
  for (int i = 0; i < 2; i++) {
#pragma unroll
    for (int jn = 0; jn < 4; jn++) {
      oac[i][jn][0] = 0.f; oac[i][jn][1] = 0.f;
      oac[i][jn][2] = 0.f; oac[i][jn][3] = 0.f;
    }
    sacc[i][0] = 0.f; sacc[i][1] = 0.f; sacc[i][2] = 0.f; sacc[i][3] = 0.f;
  }

  for (int ck = 0; ck < 4; ck++) {
    // ---- S = Q K^T (K fragments direct from global) ----
    long kf[2][16];
    f4 s[16];
#pragma unroll
    for (int i = 0; i < 2; i++) {
#pragma unroll
      for (int j = 0; j < 16; j++) {
        s[j][0] = 0.f; s[j][1] = 0.f; s[j][2] = 0.f; s[j][3] = 0.f;
      }
#pragma unroll
      for (int ksd = 0; ksd < 2; ksd++)
#pragma unroll
        for (int j = 0; j < 16; j++) {
          if (i == 0)
            kf[ksd][j] = *(const long*)(Kg + (ck << 14) +
                            (((j << 4) + r) << 6) + (((ksd << 2) + g) << 3));
          s[j] = mfma8(qf8[i][ksd], kf[ksd][j], s[j]);
        }
      // P = exp2(min(S, 8.5)) -> fp8; lane (r,g,q) holds keys 16r..16r+15
#pragma unroll
      for (int q = 0; q < 4; q++) {
        float e[16];
#pragma unroll
        for (int j = 0; j < 16; j++)
          e[j] = __builtin_amdgcn_exp2f(fminf(s[j][q], 8.5f));
        int w0 = 0, w1 = 0, w2 = 0, w3 = 0;
        w0 = __builtin_amdgcn_cvt_pk_fp8_f32(e[0],  e[1],  w0, false);
        w0 = __builtin_amdgcn_cvt_pk_fp8_f32(e[2],  e[3],  w0, true);
        w1 = __builtin_amdgcn_cvt_pk_fp8_f32(e[4],  e[5],  w1, false);
        w1 = __builtin_amdgcn_cvt_pk_fp8_f32(e[6],  e[7],  w1, true);
        w2 = __builtin_amdgcn_cvt_pk_fp8_f32(e[8],  e[9],  w2, false);
        w2 = __builtin_amdgcn_cvt_pk_fp8_f32(e[10], e[11], w2, true);
        w3 = __builtin_amdgcn_cvt_pk_fp8_f32(e[12], e[13], w3, false);
        w3 = __builtin_amdgcn_cvt_pk_fp8_f32(e[14], e[15], w3, true);
        long plo = ((long)(unsigned)w0) | ((long)w1 << 32);
        long phi = ((long)(unsigned)w2) | ((long)w3 << 32);
        int row = wbase + (i << 4) + (g << 2) + q;
        int cc = r ^ (row & 15);
        *(long*)(Ps + (row << 8) + (cc << 4))     = plo;
        *(long*)(Ps + (row << 8) + (cc << 4) + 8) = phi;
      }
    }

    // ---- O += P V, rowsum += P 1 (V fragments direct from global) ----
#pragma unroll
    for (int ks = 0; ks < 8; ks++) {
      long ap[2];
#pragma unroll
      for (int i = 0; i < 2; i++) {
        int row = wbase + (i << 4) + r;
        int cc = ((ks << 1) + (g >> 1)) ^ (row & 15);
        ap[i] = *(const long*)(Ps + (row << 8) + (cc << 4) + ((g & 1) << 3));
        sacc[i] = mfma8(ap[i], ONES, sacc[i]);
      }
#pragma unroll
      for (int jn = 0; jn < 4; jn++) {
        long bv8 = *(const long*)(Vg + (((size_t)((jn << 4) + r)) << 10) +
                                  (ck << 8) + (ks << 5) + (g << 3));
#pragma unroll
        for (int i = 0; i < 2; i++)
          oac[i][jn] = mfma8(ap[i], bv8, oac[i][jn]);
      }
    }
  }

  // epilogue: y[token, h*64+d]
#pragma unroll
  for (int i = 0; i < 2; i++)
#pragma unroll
    for (int q = 0; q < 4; q++) {
      float inv = 1.f / (sacc[i][q] + 1e-20f);
      int trow = qt0 + wbase + (i << 4) + (g << 2) + q;
      size_t base = (((size_t)(b << 10) + trow) << 9) + (h << 6);
#pragma unroll
      for (int jn = 0; jn < 4; jn++)
        yo[base + (jn << 4) + r] = f2bf(oac[i][jn][q] * inv);
    }
}

// ---------------------------------------------------------------------------
extern "C" void kernel_launch(void* const* d_in, const int* in_sizes, int n_in,
                              void* d_out, int out_size, void* d_ws, size_t ws_size,
                              hipStream_t stream)
{
  const float* q    = (const float*)d_in[0];
  const float* kv   = (const float*)d_in[1];
  const float* lnkw = (const float*)d_in[2];
  const float* lnkb = (const float*)d_in[3];
  const float* lnqw = (const float*)d_in[4];
  const float* lnqb = (const float*)d_in[5];
  const float* Wk   = (const float*)d_in[6];
  const float* bk   = (const float*)d_in[7];
  const float* Wq   = (const float*)d_in[8];
  const float* bq   = (const float*)d_in[9];
  const float* Wv   = (const float*)d_in[10];
  const float* bv   = (const float*)d_in[11];
  const float* Wp   = (const float*)d_in[12];
  const float* bp   = (const float*)d_in[13];

  char* ws = (char*)d_ws;
  const size_t SZ = (size_t)8192 * 512 * 2;      // 8 MiB stride
  short* buf0 = (short*)(ws);                    // kv_n, later reused for y
  short* qn   = (short*)(ws + SZ);
  unsigned char* kb8 = (unsigned char*)(ws + 2 * SZ);   // fp8 K image, 4 MiB
  unsigned char* qb8 = (unsigned char*)(ws + 3 * SZ);   // fp8 Q, 4 MiB
  unsigned char* vb8 = (unsigned char*)(ws + 4 * SZ);   // fp8 V image, 4 MiB
  short* Wt   = (short*)(ws + 5 * SZ);           // 4 x 512x512 bf16 = 2 MiB
  if (ws_size < 5 * SZ + 4 * 512 * 512 * 2) return;   // need 42 MiB scratch

  prep_k<<<dim3(512, 6), 256, 0, stream>>>(kv, q, lnkw, lnkb, lnqw, lnqb,
                                           Wk, Wq, Wv, Wp, buf0, qn, Wt);
  gemm_qkv_k<<<dim3(64, 4, 3), 256, 0, stream>>>(buf0, qn, Wt, bk, bq, bv,
                                                 kb8, qb8, vb8);
  attn_k<<<dim3(8, 8, 8), 256, 0, stream>>>(qb8, kb8, vb8, buf0);
  gemm_proj_k<<<dim3(64, 8), 256, 0, stream>>>(Wt + (3 << 18), buf0, bp,
                                               (float*)d_out, kv);
}

// Round 9
// 166.451 us; speedup vs baseline: 1.1456x; 1.1456x over previous
//
#include <hip/hip_runtime.h>
#include <stdint.h>

#define DI static __device__ __forceinline__

typedef __attribute__((ext_vector_type(8))) short bh8;   // 8 x bf16 (4 VGPRs)
typedef __attribute__((ext_vector_type(4))) float f4;    // MFMA accumulator

DI short f2bf(float f) {             // fp32 -> bf16 (RNE)
  unsigned u = __float_as_uint(f);
  u += 0x7fffu + ((u >> 16) & 1u);
  return (short)(u >> 16);
}

DI unsigned pkbf(float a, float b) { // [bf16(a) | bf16(b)<<16], round-half-up
  unsigned ua = __float_as_uint(a) + 0x8000u;
  unsigned ub = __float_as_uint(b) + 0x8000u;
  return __builtin_amdgcn_perm(ub, ua, 0x07060302u);
}

DI unsigned pk4fp8(float a, float b, float c, float d) { // 4 fp8 bytes
  unsigned w = 0;
  w = __builtin_amdgcn_cvt_pk_fp8_f32(a, b, w, false);
  w = __builtin_amdgcn_cvt_pk_fp8_f32(c, d, w, true);
  return w;
}

DI void gll16(const void* g, void* l) {  // 16B global -> LDS async
  __builtin_amdgcn_global_load_lds(
      (const __attribute__((address_space(1))) unsigned int*)g,
      (__attribute__((address_space(3))) unsigned int*)l, 16, 0, 0);
}

DI f4 mfma16(bh8 a, bh8 b, f4 c) {
  return __builtin_amdgcn_mfma_f32_16x16x32_bf16(a, b, c, 0, 0, 0);
}

DI f4 mfma8(long a, long b, f4 c) {  // fp8 e4m3 x e4m3, K=32
  return __builtin_amdgcn_mfma_f32_16x16x32_fp8_fp8(a, b, c, 0, 0, 0);
}

DI bh8 ld8(const short* p) { return *(const bh8*)p; }

// ---------------------------------------------------------------------------
// prep_k: fused weight-transpose (roles 0..3) + LayerNorm (roles 4..5).
// ---------------------------------------------------------------------------
__global__ __launch_bounds__(256) void prep_k(
    const float* __restrict__ kv, const float* __restrict__ qi,
    const float* __restrict__ kw, const float* __restrict__ kbv,
    const float* __restrict__ qw, const float* __restrict__ qbv,
    const float* __restrict__ Wk, const float* __restrict__ Wq,
    const float* __restrict__ Wv, const float* __restrict__ Wp,
    short* __restrict__ kvn, short* __restrict__ qn,
    short* __restrict__ Wt)
{
  __shared__ char sm[16 * 516 * 4 + 128];
  int role = blockIdx.y;
  int bx = blockIdx.x;
  int tid = threadIdx.x;

  if (role < 4) {                       // ---- weight transpose + cvt ----
    if (bx >= 256) return;
    float (*ts)[33] = (float(*)[33])sm;
    const float* w = (role == 0) ? Wk : (role == 1) ? Wq : (role == 2) ? Wv : Wp;
    short* o = Wt + ((size_t)role << 18);
    int c0 = (bx & 15) << 5, r0 = (bx >> 4) << 5;
    int tx = tid & 31, ty = tid >> 5;   // 32 x 8
#pragma unroll
    for (int k = 0; k < 32; k += 8)
      ts[ty + k][tx] = w[((size_t)(r0 + ty + k) << 9) + c0 + tx];
    __syncthreads();
#pragma unroll
    for (int k = 0; k < 32; k += 8)
      o[((size_t)(c0 + ty + k) << 9) + r0 + tx] = f2bf(ts[tx][ty + k]);
    return;
  }

  // ---- LayerNorm over C=512, fused [B,C,T] -> [token,C] transpose ----
  float (*xs)[516] = (float(*)[516])sm;
  float* smean = (float*)(sm + 16 * 516 * 4);
  float* srstd = smean + 16;
  int which = role - 4;
  const float* x = which ? qi : kv;
  const float* w = which ? qw : kw;
  const float* bb = which ? qbv : kbv;
  short* o = which ? qn : kvn;
  int b = bx >> 6;
  int t0 = (bx & 63) << 4;
  const float* xb = x + ((size_t)b << 19) + (size_t)t0;
#pragma unroll
  for (int k = 0; k < 8; k++) {
    int idx = (k << 8) + tid;            // 0..2047
    int c = idx >> 2, tt = (idx & 3) << 2;
    float4 v = *(const float4*)(xb + ((size_t)c << 10) + tt);
    xs[tt + 0][c] = v.x; xs[tt + 1][c] = v.y;
    xs[tt + 2][c] = v.z; xs[tt + 3][c] = v.w;
  }
  __syncthreads();
  {
    int t = tid >> 4, cp = tid & 15;
    float s = 0.f, s2 = 0.f;
#pragma unroll
    for (int k = 0; k < 8; k++) {
      float4 v = *(const float4*)&xs[t][(cp << 2) + (k << 6)];
      s  += v.x + v.y + v.z + v.w;
      s2 += v.x * v.x + v.y * v.y + v.z * v.z + v.w * v.w;
    }
#pragma unroll
    for (int m = 1; m < 16; m <<= 1) {
      s  += __shfl_xor(s,  m);
      s2 += __shfl_xor(s2, m);
    }
    if (cp == 0) {
      float mean = s * (1.f / 512.f);
      float var  = s2 * (1.f / 512.f) - mean * mean;
      smean[t] = mean;
      srstd[t] = rsqrtf(var + 1e-5f);
    }
  }
  __syncthreads();
#pragma unroll
  for (int k = 0; k < 8; k++) {
    int idx = (k << 8) + tid;
    int t = idx >> 7, c = (idx & 127) << 2;
    float4 v = *(const float4*)&xs[t][c];
    float4 wv = *(const float4*)(w + c);
    float4 bv4 = *(const float4*)(bb + c);
    float mu = smean[t], rs = srstd[t];
    float r0 = (v.x - mu) * rs * wv.x + bv4.x;
    float r1 = (v.y - mu) * rs * wv.y + bv4.y;
    float r2 = (v.z - mu) * rs * wv.z + bv4.z;
    float r3 = (v.w - mu) * rs * wv.w + bv4.w;
    uint2 pk; pk.x = pkbf(r0, r1); pk.y = pkbf(r2, r3);
    *(uint2*)(o + (((size_t)(b << 10) + t0 + t) << 9) + c) = pk;
  }
}

// ---------------------------------------------------------------------------
// Fused K/Q/V projection GEMM. 128x128 tile, BK=64, xor bank swizzle.
// ORIENTATION chosen so the accumulator q-quad = 4 contiguous fp8 bytes
// (one dword store per acc tile, 4x fewer epilogue stores than byte scatter):
// z=0 K: A=Wk^T (m=channel), B=kvn (n=token) -> image [bh][ck][p=pi(t)][u^(p&7)][d&7]
// z=1 Q: A=Wq^T (m=channel), B=qn  (n=token) -> image [bh][t][d] plain
// z=2 V: A=kvn (m=token), B=Wv^T (n=channel) -> image [bh][ck][d][tb^(d&31)][t&7]
// ---------------------------------------------------------------------------
__global__ __launch_bounds__(256, 3) void gemm_qkv_k(
    const short* __restrict__ kvn, const short* __restrict__ qn,
    const short* __restrict__ Wt,
    const float* __restrict__ bk, const float* __restrict__ bq,
    const float* __restrict__ bv,
    unsigned char* __restrict__ kb8, unsigned char* __restrict__ qb8,
    unsigned char* __restrict__ vb8)
{
  __shared__ short As[128 * 64];   // 16 KB
  __shared__ short Bs[128 * 64];   // 16 KB
  int z = blockIdx.z;
  const short* A; const short* Bt; const float* bias;
  int m0, n0;
  if (z == 0)      { A = Wt;             Bt = kvn;            bias = bk; }
  else if (z == 1) { A = Wt + (1 << 18); Bt = qn;             bias = bq; }
  else             { A = kvn;            Bt = Wt + (2 << 18); bias = bv; }
  if (z == 2) { m0 = blockIdx.x << 7; n0 = blockIdx.y << 7; }
  else        { m0 = blockIdx.y << 7; n0 = blockIdx.x << 7; }
  int tid = threadIdx.x;
  int lane = tid & 63, wid = tid >> 6;
  int r = lane & 15, g = lane >> 4;
  int wrow = (wid >> 1) << 6, wcol = (wid & 1) << 6;
  f4 acc[4][4];
#pragma unroll
  for (int i = 0; i < 4; i++)
#pragma unroll
    for (int j = 0; j < 4; j++) {
      acc[i][j][0] = 0.f; acc[i][j][1] = 0.f;
      acc[i][j][2] = 0.f; acc[i][j][3] = 0.f;
    }
  for (int k0 = 0; k0 < 512; k0 += 64) {
    __syncthreads();
#pragma unroll
    for (int it = 0; it < 4; it++) {
      int n = (it << 8) + tid;           // 16B-unit index, lane-contiguous
      int row = n >> 3;
      int c = (n & 7) ^ (row & 7);       // source chunk for swizzled slot
      gll16(A  + ((size_t)(m0 + row) << 9) + k0 + (c << 3), As + (n << 3));
      gll16(Bt + ((size_t)(n0 + row) << 9) + k0 + (c << 3), Bs + (n << 3));
    }
    __syncthreads();
    bh8 a[2][4], b[2][4];
#pragma unroll
    for (int ks = 0; ks < 2; ks++) {
#pragma unroll
      for (int i = 0; i < 4; i++) {
        int R = wrow + (i << 4) + r;
        a[ks][i] = ld8(As + (R << 6) + ((((ks << 2) + g) ^ (R & 7)) << 3));
      }
#pragma unroll
      for (int j = 0; j < 4; j++) {
        int R = wcol + (j << 4) + r;
        b[ks][j] = ld8(Bs + (R << 6) + ((((ks << 2) + g) ^ (R & 7)) << 3));
      }
    }
#pragma unroll
    for (int ks = 0; ks < 2; ks++)
#pragma unroll
      for (int i = 0; i < 4; i++)
#pragma unroll
        for (int j = 0; j < 4; j++)
          acc[i][j] = mfma16(a[ks][i], b[ks][j], acc[i][j]);
  }
  // epilogue: C/D layout col = lane&15, row = (lane>>4)*4 + reg
#pragma unroll
  for (int i = 0; i < 4; i++) {
#pragma unroll
    for (int j = 0; j < 4; j++) {
      int mm = m0 + wrow + (i << 4) + (g << 2);
      int nn = n0 + wcol + (j << 4) + r;
      if (z == 0) {                      // K: m=channel quad, n=token
        float4 b4 = *(const float4*)(bias + mm);
        int h = mm >> 6, d0 = mm & 63;
        int bb = nn >> 10, tt = nn & 1023;
        int c = tt & 255;
        int p = ((c & 15) << 4) | (c >> 4);
        size_t base = ((size_t)((bb * 8 + h) * 4 + (tt >> 8)) << 14);
        unsigned w = pk4fp8(acc[i][j][0] + b4.x, acc[i][j][1] + b4.y,
                            acc[i][j][2] + b4.z, acc[i][j][3] + b4.w);
        *(unsigned*)(kb8 + base + (p << 6) +
                     (((d0 >> 3) ^ (p & 7)) << 3) + (d0 & 7)) = w;
      } else if (z == 1) {               // Q: m=channel quad, n=token
        float4 b4 = *(const float4*)(bias + mm);
        int h = mm >> 6, d0 = mm & 63;
        int bb = nn >> 10, tt = nn & 1023;
        unsigned w = pk4fp8(acc[i][j][0] + b4.x, acc[i][j][1] + b4.y,
                            acc[i][j][2] + b4.z, acc[i][j][3] + b4.w);
        *(unsigned*)(qb8 + ((((size_t)(bb * 8 + h)) << 10) + tt) * 64 + d0) = w;
      } else {                           // V: m=token quad, n=channel
        float bvv = bias[nn];
        int h = nn >> 6, d = nn & 63;
        int bb = mm >> 10, tt = mm & 1023;
        int tb = (tt & 255) >> 3;
        size_t base = ((size_t)((bb * 8 + h) * 4 + (tt >> 8)) << 14);
        unsigned w = pk4fp8(acc[i][j][0] + bvv, acc[i][j][1] + bvv,
                            acc[i][j][2] + bvv, acc[i][j][3] + bvv);
        *(unsigned*)(vb8 + base + (d << 8) +
                     ((tb ^ (d & 31)) << 3) + (tt & 7)) = w;
      }
    }
  }
}

// ---------------------------------------------------------------------------
// Output projection: C[c,token] = Wp^T @ y^T, 64x128 tile, BK=64.
// ---------------------------------------------------------------------------
__global__ __launch_bounds__(256, 3) void gemm_proj_k(
    const short* __restrict__ A, const short* __restrict__ Bt,
    const float* __restrict__ bias, float* __restrict__ outp,
    const float* __restrict__ resid)
{
  __shared__ short As[64 * 64];    // 8 KB
  __shared__ short Bs[128 * 64];   // 16 KB
  int m0 = blockIdx.y << 6, n0 = blockIdx.x << 7;
  int tid = threadIdx.x;
  int lane = tid & 63, wid = tid >> 6;
  int r = lane & 15, g = lane >> 4;
  int wrow = (wid >> 1) << 5, wcol = (wid & 1) << 6;   // wave: 32 x 64
  f4 acc[2][4];
#pragma unroll
  for (int i = 0; i < 2; i++)
#pragma unroll
    for (int j = 0; j < 4; j++) {
      acc[i][j][0] = 0.f; acc[i][j][1] = 0.f;
      acc[i][j][2] = 0.f; acc[i][j][3] = 0.f;
    }
  for (int k0 = 0; k0 < 512; k0 += 64) {
    __syncthreads();
#pragma unroll
    for (int it = 0; it < 2; it++) {     // As: 512 units
      int n = (it << 8) + tid;
      int row = n >> 3;
      int c = (n & 7) ^ (row & 7);
      gll16(A + ((size_t)(m0 + row) << 9) + k0 + (c << 3), As + (n << 3));
    }
#pragma unroll
    for (int it = 0; it < 4; it++) {     // Bs: 1024 units
      int n = (it << 8) + tid;
      int row = n >> 3;
      int c = (n & 7) ^ (row & 7);
      gll16(Bt + ((size_t)(n0 + row) << 9) + k0 + (c << 3), Bs + (n << 3));
    }
    __syncthreads();
    bh8 a[2][2], b[2][4];
#pragma unroll
    for (int ks = 0; ks < 2; ks++) {
#pragma unroll
      for (int i = 0; i < 2; i++) {
        int R = wrow + (i << 4) + r;
        a[ks][i] = ld8(As + (R << 6) + ((((ks << 2) + g) ^ (R & 7)) << 3));
      }
#pragma unroll
      for (int j = 0; j < 4; j++) {
        int R = wcol + (j << 4) + r;
        b[ks][j] = ld8(Bs + (R << 6) + ((((ks << 2) + g) ^ (R & 7)) << 3));
      }
    }
#pragma unroll
    for (int ks = 0; ks < 2; ks++)
#pragma unroll
      for (int i = 0; i < 2; i++)
#pragma unroll
        for (int j = 0; j < 4; j++)
          acc[i][j] = mfma16(a[ks][i], b[ks][j], acc[i][j]);
  }
#pragma unroll
  for (int i = 0; i < 2; i++) {
#pragma unroll
    for (int j = 0; j < 4; j++) {
      int mm = m0 + wrow + (i << 4) + (g << 2);
      int nn = n0 + wcol + (j << 4) + r;
      int bb = nn >> 10, t = nn & 1023;
#pragma unroll
      for (int q = 0; q < 4; q++) {
        int m = mm + q;
        size_t ad = ((((size_t)bb << 9) + m) << 10) + t;
        outp[ad] = acc[i][j][q] + bias[m] + resid[ad];
      }
    }
  }
}

// ---------------------------------------------------------------------------
// Flash attention (R7-proven): fp8 K/V arrive PRE-SWIZZLED in global memory
// (producer-baked LDS image) -> staging is an identity 16B DMA, zero cvt VALU.
// Q read as fp8 b64 directly. Softmax exp2(min(S*csc-3, 8.5)) (clamp: e4m3fn
// overflow = NaN, cvt does not saturate); rowsum via ones-MFMA; P fp8 in LDS.
// block = 256 (4 waves); wave owns 32 q-rows; chunk = 256 keys, 4 chunks.
// LDS: Ks 16KB + Vs 16KB + Ps 32KB = 64KB -> 2 blocks/CU.
// ---------------------------------------------------------------------------
__global__ __launch_bounds__(256, 2) void attn_k(
    const unsigned char* __restrict__ qb8, const unsigned char* __restrict__ kb8,
    const unsigned char* __restrict__ vb8, short* __restrict__ yo)
{
  __shared__ char Ks[16384];       // [p][u^(p&7)] fp8 image from global
  __shared__ char Vs[16384];       // [d][tb^(d&31)] fp8
  __shared__ char Ps[32768];       // [row][256 key fp8], 16B-chunk xor (row&15)
  int h = blockIdx.x, b = blockIdx.z;
  int qt0 = blockIdx.y << 7;
  int tid = threadIdx.x, lane = tid & 63, wid = tid >> 6;
  int r = lane & 15, g = lane >> 4;
  int wbase = wid << 5;
  size_t bh = (size_t)(b * 8 + h);
  const unsigned char* Qg = qb8 + ((bh << 10) + qt0) * 64;
  const unsigned char* Kg = kb8 + (bh << 16);     // 4 chunks x 16 KB
  const unsigned char* Vg = vb8 + (bh << 16);

  // Q A-fragments: direct fp8 b64 loads (no conversion)
  long qf8[2][2];
#pragma unroll
  for (int i = 0; i < 2; i++)
#pragma unroll
    for (int ksd = 0; ksd < 2; ksd++)
      qf8[i][ksd] = *(const long*)(Qg +
          ((size_t)(wbase + (i << 4) + r) << 6) + (((ksd << 2) + g) << 3));

  const long ONES = 0x3838383838383838L;   // fp8 e4m3 1.0 x8

  f4 oac[2][4], sacc[2];
#pragma unroll
  for (int i = 0; i < 2; i++) {
#pragma unroll
    for (int jn = 0; jn < 4; jn++) {
      oac[i][jn][0] = 0.f; oac[i][jn][1] = 0.f;
      oac[i][jn][2] = 0.f; oac[i][jn][3] = 0.f;
    }
    sacc[i][0] = 0.f; sacc[i][1] = 0.f; sacc[i][2] = 0.f; sacc[i][3] = 0.f;
  }

  const float csc = 0.18033688011112042f;   // log2(e)/8

  for (int ck = 0; ck < 4; ck++) {
    __syncthreads();
#pragma unroll
    for (int it = 0; it < 4; it++) {     // identity DMA: global image -> LDS
      int n = ((it << 8) + tid) << 4;
      gll16(Kg + (ck << 14) + n, Ks + n);
      gll16(Vg + (ck << 14) + n, Vs + n);
    }
    __syncthreads();

    // ---- S = Q K^T, P = exp2(min(S*csc - 3, 8.5)) -> fp8, per i-subtile ----
    long kf[2][16];
    f4 s[16];
#pragma unroll
    for (int i = 0; i < 2; i++) {
#pragma unroll
      for (int j = 0; j < 16; j++) {
        s[j][0] = 0.f; s[j][1] = 0.f; s[j][2] = 0.f; s[j][3] = 0.f;
      }
#pragma unroll
      for (int ksd = 0; ksd < 2; ksd++)
#pragma unroll
        for (int j = 0; j < 16; j++) {
          if (i == 0)
            kf[ksd][j] = *(const long*)(Ks + (((j << 4) + r) << 6) +
                            ((((ksd << 2) + g) ^ (r & 7)) << 3));
          s[j] = mfma8(qf8[i][ksd], kf[ksd][j], s[j]);
        }
      // pack: lane (r,g,q) holds keys 16r..16r+15 (j ascending)
#pragma unroll
      for (int q = 0; q < 4; q++) {
        float e[16];
#pragma unroll
        for (int j = 0; j < 16; j++)
          e[j] = __builtin_amdgcn_exp2f(
                     fminf(fmaf(s[j][q], csc, -3.0f), 8.5f));
        int w0 = 0, w1 = 0, w2 = 0, w3 = 0;
        w0 = __builtin_amdgcn_cvt_pk_fp8_f32(e[0],  e[1],  w0, false);
        w0 = __builtin_amdgcn_cvt_pk_fp8_f32(e[2],  e[3],  w0, true);
        w1 = __builtin_amdgcn_cvt_pk_fp8_f32(e[4],  e[5],  w1, false);
        w1 = __builtin_amdgcn_cvt_pk_fp8_f32(e[6],  e[7],  w1, true);
        w2 = __builtin_amdgcn_cvt_pk_fp8_f32(e[8],  e[9],  w2, false);
        w2 = __builtin_amdgcn_cvt_pk_fp8_f32(e[10], e[11], w2, true);
        w3 = __builtin_amdgcn_cvt_pk_fp8_f32(e[12], e[13], w3, false);
        w3 = __builtin_amdgcn_cvt_pk_fp8_f32(e[14], e[15], w3, true);
        long plo = ((long)(unsigned)w0) | ((long)w1 << 32);
        long phi = ((long)(unsigned)w2) | ((long)w3 << 32);
        int row = wbase + (i << 4) + (g << 2) + q;
        int cc = r ^ (row & 15);
        *(long*)(Ps + (row << 8) + (cc << 4))     = plo;
        *(long*)(Ps + (row << 8) + (cc << 4) + 8) = phi;
      }
    }

    // ---- O += P V, rowsum += P 1 (wave reads only rows it wrote) ----
#pragma unroll
    for (int ks = 0; ks < 8; ks++) {
      long ap[2];
#pragma unroll
      for (int i = 0; i < 2; i++) {
        int row = wbase + (i << 4) + r;
        int cc = ((ks << 1) + (g >> 1)) ^ (row & 15);
        ap[i] = *(const long*)(Ps + (row << 8) + (cc << 4) + ((g & 1) << 3));
        sacc[i] = mfma8(ap[i], ONES, sacc[i]);
      }
#pragma unroll
      for (int jn = 0; jn < 4; jn++) {
        int d = (jn << 4) + r;
        long bv8 = *(const long*)(Vs + (d << 8) +
                      ((((ks << 2) + g) ^ (d & 31)) << 3));
#pragma unroll
        for (int i = 0; i < 2; i++)
          oac[i][jn] = mfma8(ap[i], bv8, oac[i][jn]);
      }
    }
  }

  // epilogue: y[token, h*64+d]
#pragma unroll
  for (int i = 0; i < 2; i++)
#pragma unroll
    for (int q = 0; q < 4; q++) {
      float inv = 1.f / (sacc[i][q] + 1e-20f);
      int trow = qt0 + wbase + (i << 4) + (g << 2) + q;
      size_t base = (((size_t)(b << 10) + trow) << 9) + (h << 6);
#pragma unroll
      for (int jn = 0; jn < 4; jn++)
        yo[base + (jn << 4) + r] = f2bf(oac[i][jn][q] * inv);
    }
}

// ---------------------------------------------------------------------------
extern "C" void kernel_launch(void* const* d_in, const int* in_sizes, int n_in,
                              void* d_out, int out_size, void* d_ws, size_t ws_size,
                              hipStream_t stream)
{
  const float* q    = (const float*)d_in[0];
  const float* kv   = (const float*)d_in[1];
  const float* lnkw = (const float*)d_in[2];
  const float* lnkb = (const float*)d_in[3];
  const float* lnqw = (const float*)d_in[4];
  const float* lnqb = (const float*)d_in[5];
  const float* Wk   = (const float*)d_in[6];
  const float* bk   = (const float*)d_in[7];
  const float* Wq   = (const float*)d_in[8];
  const float* bq   = (const float*)d_in[9];
  const float* Wv   = (const float*)d_in[10];
  const float* bv   = (const float*)d_in[11];
  const float* Wp   = (const float*)d_in[12];
  const float* bp   = (const float*)d_in[13];

  char* ws = (char*)d_ws;
  const size_t SZ = (size_t)8192 * 512 * 2;      // 8 MiB stride
  short* buf0 = (short*)(ws);                    // kv_n, later reused for y
  short* qn   = (short*)(ws + SZ);
  unsigned char* kb8 = (unsigned char*)(ws + 2 * SZ);   // fp8 K image, 4 MiB
  unsigned char* qb8 = (unsigned char*)(ws + 3 * SZ);   // fp8 Q, 4 MiB
  unsigned char* vb8 = (unsigned char*)(ws + 4 * SZ);   // fp8 V image, 4 MiB
  short* Wt   = (short*)(ws + 5 * SZ);           // 4 x 512x512 bf16 = 2 MiB
  if (ws_size < 5 * SZ + 4 * 512 * 512 * 2) return;   // need 42 MiB scratch

  prep_k<<<dim3(512, 6), 256, 0, stream>>>(kv, q, lnkw, lnkb, lnqw, lnqb,
                                           Wk, Wq, Wv, Wp, buf0, qn, Wt);
  gemm_qkv_k<<<dim3(64, 4, 3), 256, 0, stream>>>(buf0, qn, Wt, bk, bq, bv,
                                                 kb8, qb8, vb8);
  attn_k<<<dim3(8, 8, 8), 256, 0, stream>>>(qb8, kb8, vb8, buf0);
  gemm_proj_k<<<dim3(64, 8), 256, 0, stream>>>(Wt + (3 << 18), buf0, bp,
                                               (float*)d_out, kv);
}